// Round 3
// baseline (250.542 us; speedup 1.0000x reference)
//
#include <hip/hip_runtime.h>

#define C_CLASSES 2048
#define F_EMBED   128
#define N_ROWS    16384

constexpr float TAU    = 32.0f;
constexpr float ALPHA  = 0.9f;
constexpr float ZSHIFT = 64.0f;   // fixed logit shift: z = -TAU*D in [-128,0]

typedef __bf16 bf16x8 __attribute__((ext_vector_type(8)));
typedef float  f32x4  __attribute__((ext_vector_type(4)));

__device__ __forceinline__ float wsum64(float v) {
#pragma unroll
  for (int m = 1; m < 64; m <<= 1) v += __shfl_xor(v, m, 64);
  return v;
}

// ---------------- prep: per-class data ----------------
// mu = l2norm(means[c]); ic = exp(-clip(lv,0,6)); w2 = -2*mu*ic; s3 = sum mu^2*ic
__global__ __launch_bounds__(256) void prep_classes_k(
    const float* __restrict__ means, const float* __restrict__ log_vars,
    __bf16* __restrict__ icb, __bf16* __restrict__ w2b,
    float* __restrict__ s3, float* __restrict__ out0) {
  const int c    = blockIdx.x * 4 + (threadIdx.x >> 6);
  const int lane = threadIdx.x & 63;
  const size_t base = (size_t)c * F_EMBED;
  const float m0 = means[base + lane], m1 = means[base + lane + 64];
  const float ss = wsum64(m0 * m0 + m1 * m1);
  const float inv = 1.0f / fmaxf(sqrtf(ss), 1e-12f);
  const float mu0 = m0 * inv, mu1 = m1 * inv;
  const float lv0 = fminf(fmaxf(log_vars[base + lane], 0.0f), 6.0f);
  const float lv1 = fminf(fmaxf(log_vars[base + lane + 64], 0.0f), 6.0f);
  const float ic0 = __expf(-lv0), ic1 = __expf(-lv1);
  const float s3p = wsum64(mu0 * mu0 * ic0 + mu1 * mu1 * ic1);
  icb[base + lane]      = (__bf16)ic0;
  icb[base + lane + 64] = (__bf16)ic1;
  w2b[base + lane]      = (__bf16)(-2.0f * mu0 * ic0);
  w2b[base + lane + 64] = (__bf16)(-2.0f * mu1 * ic1);
  if (lane == 0) s3[c] = s3p;
  if (c == 0 && lane == 0) out0[0] = 0.0f;  // loss accumulator (d_out is poisoned each call)
}

// ---------------- prep: per-row data ----------------
// xn = l2norm(X[n]) -> bf16; xn2 = xn*xn -> bf16
__global__ __launch_bounds__(256) void prep_rows_k(
    const float* __restrict__ X, __bf16* __restrict__ xnb, __bf16* __restrict__ xn2b) {
  const int n    = blockIdx.x * 4 + (threadIdx.x >> 6);
  const int lane = threadIdx.x & 63;
  const size_t base = (size_t)n * F_EMBED;
  const float x0 = X[base + lane], x1 = X[base + lane + 64];
  const float ss = wsum64(x0 * x0 + x1 * x1);
  const float inv = 1.0f / fmaxf(sqrtf(ss), 1e-12f);
  const float a0 = x0 * inv, a1 = x1 * inv;
  xnb[base + lane]       = (__bf16)a0;
  xnb[base + lane + 64]  = (__bf16)a1;
  xn2b[base + lane]      = (__bf16)(a0 * a0);
  xn2b[base + lane + 64] = (__bf16)(a1 * a1);
}

// ---------------- fused main: D -> (H write, logsumexp, D_T) ----------------
// Grid: N/64 blocks of 512 threads (8 waves). Block owns 64 rows; wave w owns
// classes [w*256, w*256+256) in 16-class tiles. A-fragments register-resident.
__global__ __launch_bounds__(512, 2) void mahal_main_k(
    const __bf16* __restrict__ xnb, const __bf16* __restrict__ xn2b,
    const __bf16* __restrict__ icb, const __bf16* __restrict__ w2b,
    const float* __restrict__ s3, const int* __restrict__ T,
    float* __restrict__ out) {
  __shared__ int   Tl[64];
  __shared__ float LsLDS[8][64];
  __shared__ float DtLDS[8][64];
  const int tid  = threadIdx.x;
  const int w    = tid >> 6;
  const int lane = tid & 63;
  const int lo   = lane & 15;
  const int hi   = lane >> 4;
  const int rowbase = blockIdx.x * 64;
  if (tid < 64) Tl[tid] = T[rowbase + tid];
  __syncthreads();

  // A fragments: lane holds A[row = rg*16+lo][k = kg*32 + hi*8 + j]
  bf16x8 axn[4][4], ax2[4][4];
#pragma unroll
  for (int rg = 0; rg < 4; ++rg) {
#pragma unroll
    for (int kg = 0; kg < 4; ++kg) {
      const size_t off = (size_t)(rowbase + rg * 16 + lo) * F_EMBED + kg * 32 + hi * 8;
      axn[rg][kg] = *(const bf16x8*)(xnb + off);
      ax2[rg][kg] = *(const bf16x8*)(xn2b + off);
    }
  }
  // target class per (rg, reg): D row = rg*16 + hi*4 + reg
  int tT[4][4];
#pragma unroll
  for (int rg = 0; rg < 4; ++rg)
#pragma unroll
    for (int r = 0; r < 4; ++r) tT[rg][r] = Tl[rg * 16 + hi * 4 + r];

  float lsum[4][4], dTv[4][4];
#pragma unroll
  for (int rg = 0; rg < 4; ++rg)
#pragma unroll
    for (int r = 0; r < 4; ++r) { lsum[rg][r] = 0.0f; dTv[rg][r] = 0.0f; }

  const int cbase = w * 256;
  for (int ct = 0; ct < 16; ++ct) {
    const int cb  = cbase + ct * 16;
    const int col = cb + lo;
    f32x4 acc[4];
#pragma unroll
    for (int rg = 0; rg < 4; ++rg) acc[rg] = (f32x4){0.0f, 0.0f, 0.0f, 0.0f};
    // B fragments: lane holds B[k = kg*32 + hi*8 + j][col = lo] = classdata[col][k]
    const size_t cboff = (size_t)col * F_EMBED + hi * 8;
#pragma unroll
    for (int kg = 0; kg < 4; ++kg) {
      const bf16x8 bic = *(const bf16x8*)(icb + cboff + kg * 32);
      const bf16x8 bw2 = *(const bf16x8*)(w2b + cboff + kg * 32);
#pragma unroll
      for (int rg = 0; rg < 4; ++rg) {
        acc[rg] = __builtin_amdgcn_mfma_f32_16x16x32_bf16(ax2[rg][kg], bic, acc[rg], 0, 0, 0);
        acc[rg] = __builtin_amdgcn_mfma_f32_16x16x32_bf16(axn[rg][kg], bw2, acc[rg], 0, 0, 0);
      }
    }
    const float s3c = s3[col];
#pragma unroll
    for (int rg = 0; rg < 4; ++rg) {
#pragma unroll
      for (int r = 0; r < 4; ++r) {
        const float D   = acc[rg][r] + s3c;
        const int   row = rowbase + rg * 16 + hi * 4 + r;
        const bool  isT = (col == tT[rg][r]);
        const float h   = isT ? 1.0f : __expf(-ALPHA * D);
        out[1 + (size_t)row * C_CLASSES + col] = h;
        lsum[rg][r] += __expf(ZSHIFT - TAU * D);
        if (isT) dTv[rg][r] += D;
      }
    }
  }

  // reduce partial (lsum, D_T) across the 16 lo-lanes holding each row
#pragma unroll
  for (int rg = 0; rg < 4; ++rg) {
#pragma unroll
    for (int r = 0; r < 4; ++r) {
      float L = lsum[rg][r], Dv = dTv[rg][r];
#pragma unroll
      for (int m = 1; m < 16; m <<= 1) {
        L  += __shfl_xor(L, m, 64);
        Dv += __shfl_xor(Dv, m, 64);
      }
      if (lo == 0) {
        LsLDS[w][rg * 16 + hi * 4 + r] = L;
        DtLDS[w][rg * 16 + hi * 4 + r] = Dv;
      }
    }
  }
  __syncthreads();
  if (tid < 64) {
    float L = 0.0f, Dv = 0.0f;
#pragma unroll
    for (int ww = 0; ww < 8; ++ww) { L += LsLDS[ww][tid]; Dv += DtLDS[ww][tid]; }
    float loss = TAU * Dv + logf(L) - ZSHIFT;  // -logp[n, T[n]]
    loss = wsum64(loss);
    if (tid == 0) atomicAdd(out, loss * (1.0f / N_ROWS));
  }
}

extern "C" void kernel_launch(void* const* d_in, const int* in_sizes, int n_in,
                              void* d_out, int out_size, void* d_ws, size_t ws_size,
                              hipStream_t stream) {
  const float* X        = (const float*)d_in[0];
  const int*   T        = (const int*)d_in[1];
  const float* means    = (const float*)d_in[2];
  const float* log_vars = (const float*)d_in[3];
  float* out = (float*)d_out;

  // workspace layout (~9.02 MB total, 16B-aligned chunks)
  char* ws = (char*)d_ws;
  __bf16* icb  = (__bf16*)ws;                                   // 512 KB
  __bf16* w2b  = (__bf16*)(ws + (512u << 10));                  // 512 KB
  float*  s3   = (float*)(ws + (1u << 20));                     // 8 KB
  __bf16* xnb  = (__bf16*)(ws + (1u << 20) + (16u << 10));      // 4 MB
  __bf16* xn2b = (__bf16*)(ws + (1u << 20) + (16u << 10) + (4u << 20)); // 4 MB

  prep_classes_k<<<C_CLASSES / 4, 256, 0, stream>>>(means, log_vars, icb, w2b, s3, out);
  prep_rows_k<<<N_ROWS / 4, 256, 0, stream>>>(X, xnb, xn2b);
  mahal_main_k<<<N_ROWS / 64, 512, 0, stream>>>(xnb, xn2b, icb, w2b, s3, T, out);
}